// Round 9
// baseline (419.340 us; speedup 1.0000x reference)
//
#include <hip/hip_runtime.h>
#include <cmath>

// K[n,m] = sv^2 * sum_p (x1[n,p]-off)*(x2[m,p]-off) + sb^2,  N=M=8192, P=16.
// Output 256 MiB fp32. Harness fill proves 6.5 TB/s on these boxes.
//
// R9 = R8 resubmitted verbatim (R8 was an infrastructure failure; the
// experiment never ran). R8 = R0's exact structure (the only
// twice-reproduced best: 273.5/274.3) with the last untested mechanism
// removed: per-block serialization.
//   - R0: 4096 blocks, each stages BOTH tiles, one full __syncthreads
//     (= s_waitcnt vmcnt(0) lgkmcnt(0) drain) per block, burst store tail.
//   - R8: 1024 blocks (whole grid co-resident, 4/CU = 16 waves/CU, same as
//     R0), each handles 4 consecutive m-tiles: x1 tile staged ONCE (4x
//     reuse), x2 tiles double-buffered with issue-early/write-late prefetch
//     (T14), and inter-tile sync via raw s_barrier + lgkmcnt(0) ONLY --
//     no vmcnt drain, so tile k's store burst and tile k+1's prefetch
//     loads stay in flight across the barrier.
// Everything else is byte-identical to R0's winning recipe: 128x128 tile,
// 256 threads, acc[8][8], transposed padded LDS (stride 132), plain stores.
// sv folded into staged tiles (R7 verified numerics: same absmax).

typedef float f32x4 __attribute__((ext_vector_type(4)));

#define TILE   128
#define LDST   132     // padded row stride (floats)
#define MTILES 4       // consecutive m-tiles per block

__global__ __launch_bounds__(256, 4) void linear_kernel(
    const float* __restrict__ x1, const float* __restrict__ x2,
    const float* __restrict__ p_lsb, const float* __restrict__ p_lsv,
    const float* __restrict__ p_off, float* __restrict__ out, int m)
{
    __shared__ float s1[16 * LDST];        // sv*(x1[n0+row][p]-off), [p][row]
    __shared__ float s2[2][16 * LDST];     // double-buffered x2 tiles

    const int tid = threadIdx.x;
    const int tx  = tid & 15;              // column group
    const int ty  = tid >> 4;              // row group
    const int n0  = blockIdx.y * TILE;
    const int mg  = blockIdx.x * MTILES;   // first m-tile index

    const float off = p_off[0];
    const float sv  = expf(p_lsv[0]);
    const float sb  = expf(p_lsb[0]);
    const float sb2 = sb * sb;

    // ---- Stage s1 (once) and s2[0]: scaled + transposed ----
    {
        const f32x4* g1 = (const f32x4*)(x1 + (size_t)n0 * 16);
        const f32x4* g2 = (const f32x4*)(x2 + (size_t)(mg * TILE) * 16);
        #pragma unroll
        for (int j = tid; j < 512; j += 256) {
            const int row = j >> 2;
            const int p0  = (j & 3) * 4;
            const f32x4 v = g1[j];
            const f32x4 w = g2[j];
            #pragma unroll
            for (int jj = 0; jj < 4; ++jj) {
                s1[(p0 + jj) * LDST + row]    = sv * (v[jj] - off);
                s2[0][(p0 + jj) * LDST + row] = sv * (w[jj] - off);
            }
        }
    }
    asm volatile("s_waitcnt lgkmcnt(0)" ::: "memory");
    __builtin_amdgcn_s_barrier();
    __builtin_amdgcn_sched_barrier(0);

    int cur = 0;
    #pragma unroll
    for (int mt = 0; mt < MTILES; ++mt) {
        // ---- Issue next x2 tile's global loads EARLY (write-late, T14) ----
        f32x4 pf0, pf1;
        if (mt < MTILES - 1) {
            const f32x4* gn =
                (const f32x4*)(x2 + (size_t)((mg + mt + 1) * TILE) * 16);
            pf0 = gn[tid];
            pf1 = gn[tid + 256];
        }

        // ---- Rank-16 accumulation from s1, s2[cur] (R0's exact pattern) ----
        float acc[8][8];
        #pragma unroll
        for (int r = 0; r < 8; ++r)
            #pragma unroll
            for (int c = 0; c < 8; ++c) acc[r][c] = 0.0f;

        const float* s2c = s2[cur];
        #pragma unroll
        for (int p = 0; p < 16; ++p) {
            const float* s1p = &s1[p * LDST];
            const float* s2p = &s2c[p * LDST];
            const f32x4 a0 = *(const f32x4*)&s1p[ty * 4];
            const f32x4 a1 = *(const f32x4*)&s1p[64 + ty * 4];
            const f32x4 b0 = *(const f32x4*)&s2p[tx * 4];
            const f32x4 b1 = *(const f32x4*)&s2p[64 + tx * 4];
            const float av[8] = {a0[0], a0[1], a0[2], a0[3],
                                 a1[0], a1[1], a1[2], a1[3]};
            const float bv[8] = {b0[0], b0[1], b0[2], b0[3],
                                 b1[0], b1[1], b1[2], b1[3]};
            #pragma unroll
            for (int r = 0; r < 8; ++r)
                #pragma unroll
                for (int c = 0; c < 8; ++c)
                    acc[r][c] = fmaf(av[r], bv[c], acc[r][c]);
        }

        // ---- Burst store of tile mt (plain stores; drain in background) ----
        {
            const int m0 = (mg + mt) * TILE;
            #pragma unroll
            for (int r = 0; r < 8; ++r) {
                const int lr = (r < 4) ? (ty * 4 + r) : (64 + ty * 4 + (r - 4));
                float* orow = out + (size_t)(n0 + lr) * m + m0;
                f32x4 o0, o1;
                #pragma unroll
                for (int c = 0; c < 4; ++c) {
                    o0[c] = acc[r][c] + sb2;
                    o1[c] = acc[r][4 + c] + sb2;
                }
                *(f32x4*)&orow[tx * 4]      = o0;
                *(f32x4*)&orow[64 + tx * 4] = o1;
            }
        }

        // ---- Write prefetched tile into the other buffer; LDS-only barrier ----
        if (mt < MTILES - 1) {
            float* s2n = s2[cur ^ 1];
            const int row = tid >> 2;
            const int p0  = (tid & 3) * 4;
            #pragma unroll
            for (int jj = 0; jj < 4; ++jj) {
                s2n[(p0 + jj) * LDST + row]      = sv * (pf0[jj] - off);
                s2n[(p0 + jj) * LDST + row + 64] = sv * (pf1[jj] - off);
            }
            asm volatile("s_waitcnt lgkmcnt(0)" ::: "memory");
            __builtin_amdgcn_s_barrier();
            __builtin_amdgcn_sched_barrier(0);
            cur ^= 1;
        }
    }
}

extern "C" void kernel_launch(void* const* d_in, const int* in_sizes, int n_in,
                              void* d_out, int out_size, void* d_ws, size_t ws_size,
                              hipStream_t stream) {
    const float* x1  = (const float*)d_in[0];
    const float* x2  = (const float*)d_in[1];
    const float* lsb = (const float*)d_in[2];
    const float* lsv = (const float*)d_in[3];
    const float* off = (const float*)d_in[4];
    float* out = (float*)d_out;

    const int n = in_sizes[0] / 16;   // 8192
    const int m = in_sizes[1] / 16;   // 8192

    dim3 grid(m / (TILE * MTILES), n / TILE);   // 16 x 64 = 1024 blocks
    linear_kernel<<<grid, 256, 0, stream>>>(x1, x2, lsb, lsv, off, out, m);
}